// Round 5
// baseline (812.583 us; speedup 1.0000x reference)
//
#include <hip/hip_runtime.h>

#define BB 8
#define LL 2048
#define DD 512
#define QQ 8
#define KK 2048
#define MM (BB*LL)      // 16384 points

#define BMt 128         // block tile M (2 wr-waves x 64)
#define BNt 128         // block tile N (2 wc-waves x 64)
#define NSTEPS 16       // DD/32
#define NTILES (KK/BNt) // 16
#define MTILES (MM/BMt) // 128

typedef __attribute__((ext_vector_type(8))) short short8;
typedef __attribute__((ext_vector_type(4))) float f32x4;

#define GLDS(src, dst) __builtin_amdgcn_global_load_lds( \
    (const __attribute__((address_space(1))) void*)(src), \
    (__attribute__((address_space(3))) void*)(dst), 16, 0, 0)

__device__ __forceinline__ ushort f2bf(float f) {
    uint u = __float_as_uint(f);
    u += 0x7FFFu + ((u >> 16) & 1u);
    return (ushort)(u >> 16);
}

// ---------------- cb2: fp32 squared norms ----------------
__global__ __launch_bounds__(256) void cb2_kernel(const float* __restrict__ cb,
                                                  float* __restrict__ cb2) {
    int row  = blockIdx.x * 4 + (threadIdx.x >> 6);
    int lane = threadIdx.x & 63;
    const float* r = cb + (size_t)row * DD + lane * 8;
    float4 a = *(const float4*)r;
    float4 b = *(const float4*)(r + 4);
    float s = a.x*a.x + a.y*a.y + a.z*a.z + a.w*a.w
            + b.x*b.x + b.y*b.y + b.z*b.z + b.w*b.w;
    #pragma unroll
    for (int off = 32; off >= 1; off >>= 1) s += __shfl_xor(s, off);
    if (lane == 0) cb2[row] = s;
}

// ---------------- codebook hi-part, wave-contiguous frag order ----------------
// frag idx = (nt*16+ks)*512 + colblk*64 + kk*16 + colr   (nt: 16 tiles of 128 cols)
__global__ __launch_bounds__(256) void bprep_kernel(const float* __restrict__ cbq,
                                                    short8* __restrict__ bh) {
    int r = blockIdx.x * 256 + threadIdx.x;   // 0..131071, write-coalesced
    int colr   = r & 15;
    int kk     = (r >> 4) & 3;
    int colblk = (r >> 6) & 7;
    int ks     = (r >> 9) & 15;
    int nt     = r >> 13;
    const float* src = cbq + (size_t)(nt * 128 + colblk * 16 + colr) * DD + ks * 32 + kk * 8;
    float f[8];
    *(float4*)&f[0] = *(const float4*)src;
    *(float4*)&f[4] = *(const float4*)(src + 4);
    short8 h8;
    #pragma unroll
    for (int j = 0; j < 8; j++) h8[j] = (short)f2bf(f[j]);
    bh[r] = h8;
}

// ---------------- level-0 A prep: resid <- x, ah <- bf16(x) [row][lane] ----------------
// ah layout: ah[row*64 + j] holds bf16 of resid[row][j*8 .. j*8+8)  (identity: j = d/8)
__global__ __launch_bounds__(256) void aprep0_kernel(const float* __restrict__ x,
                                                     float* __restrict__ resid,
                                                     short8* __restrict__ ah) {
    const int wid  = threadIdx.x >> 6;
    const int lane = threadIdx.x & 63;
    const int row  = blockIdx.x * 4 + wid;
    const float* src = x + (size_t)row * DD + lane * 8;
    float4 v0 = *(const float4*)src;
    float4 v1 = *(const float4*)(src + 4);
    float* dst = resid + (size_t)row * DD + lane * 8;
    *(float4*)dst       = v0;
    *(float4*)(dst + 4) = v1;
    short8 h;
    h[0] = (short)f2bf(v0.x); h[1] = (short)f2bf(v0.y);
    h[2] = (short)f2bf(v0.z); h[3] = (short)f2bf(v0.w);
    h[4] = (short)f2bf(v1.x); h[5] = (short)f2bf(v1.y);
    h[6] = (short)f2bf(v1.z); h[7] = (short)f2bf(v1.w);
    ah[(size_t)row * 64 + lane] = h;
}

// ---------------- 1-term bf16 GEMM + per-tile (v1, candidate bitmask) ----------------
// B-only LDS (2 x 8 KB double-buffer via global_load_lds); A-frags loaded DIRECTLY
// global->VGPR from row-major ah (lane l: row wr*64+m*16+(l&15), 16B chunk l>>4),
// register-double-buffered across K-steps. Halves LDS traffic and removes the
// 8-way A-read bank conflict. Epilogue: tile-min, mask, coalesced phase-C write.
__global__ __launch_bounds__(256, 4) void gemm_argmin_kernel(
    const short8* __restrict__ ah,
    const short8* __restrict__ bh,
    const float*  __restrict__ cb2q,
    float*        __restrict__ blockv1,    // [NTILES][MM]
    uint4*        __restrict__ blockmask,  // [NTILES][MM]
    float W)
{
    __shared__ short8 smem[2][512];   // 16 KB: B double-buffer only

    const int id   = blockIdx.x;
    const int xcd  = id & 7;
    const int slot = id >> 3;            // 0..255
    const int nt   = slot & 15;
    const int mt   = xcd * 16 + (slot >> 4);

    const int t    = threadIdx.x;
    const int wid  = t >> 6;
    const int lane = t & 63;
    const int wr   = wid >> 1, wc = wid & 1;
    const int l15  = lane & 15, l4 = lane >> 4;

    // acc[n][m]: codebook-col frag n, point-row frag m (operand-swapped MFMA)
    f32x4 acc[4][4];
    #pragma unroll
    for (int n = 0; n < 4; n++)
        #pragma unroll
        for (int m = 0; m < 4; m++) acc[n][m] = (f32x4){0.f, 0.f, 0.f, 0.f};

    const char* bSrc = (const char*)bh + (size_t)nt * 131072;
    // per-lane A base: row = mt*128 + wr*64 + l15, chunk l4 (16B of the 64B/step)
    const char* aW = (const char*)ah
                   + ((size_t)(mt * 128 + wr * 64 + l15) << 10) + (l4 << 4);

    auto STAGE = [&](int ks, int buf) {
        char* dst = (char*)&smem[buf][0];
        const char* bs = bSrc + (size_t)ks * 8192;
        #pragma unroll
        for (int j = 0; j < 2; j++) {
            int c = wid * 2 + j;
            GLDS(bs + c * 1024 + lane * 16, dst + c * 1024);
        }
    };
    auto LOADA = [&](short8* af, int ks) {
        #pragma unroll
        for (int m = 0; m < 4; m++)
            af[m] = *(const short8*)(aW + m * 16384 + ks * 64);
    };
    auto COMPUTE = [&](int buf, const short8* af) {
        short8 bf[4];
        #pragma unroll
        for (int n = 0; n < 4; n++)
            bf[n] = smem[buf][wc * 256 + n * 64 + lane];   // lane-contiguous: no conflict
        #pragma unroll
        for (int n = 0; n < 4; n++)
            #pragma unroll
            for (int m = 0; m < 4; m++)
                acc[n][m] = __builtin_amdgcn_mfma_f32_16x16x32_bf16(bf[n], af[m], acc[n][m], 0, 0, 0);
    };

    short8 afA[4], afB[4];
    STAGE(0, 0);
    LOADA(afA, 0);

    for (int ks = 0; ks < NSTEPS; ks += 2) {
        __syncthreads();                       // buf0(ks) staged
        STAGE(ks + 1, 1);                      // ks+1 <= 15 always
        LOADA(afB, ks + 1);
        COMPUTE(0, afA);
        __syncthreads();                       // buf1(ks+1) staged
        if (ks + 2 < NSTEPS) { STAGE(ks + 2, 0); LOADA(afA, ks + 2); }
        COMPUTE(1, afB);
    }

    // ---- epilogue ----
    // acc[n][m][r]: row = wr*64 + m*16 + l15 ; col = wc*64 + n*16 + l4*4 + r
    // Last compute read smem[1]; scratch lives in smem[0]; all smem[0] reads
    // finished before the final in-loop barrier -> no barrier needed here.
    float* halfmin = (float*)&smem[0][0];                       // [128][2] floats, 1 KB
    uint2* maskS   = (uint2*)((char*)&smem[0][0] + 1024);       // [128][2] uint2, 2 KB

    f32x4 c2v[4];
    #pragma unroll
    for (int n = 0; n < 4; n++)
        c2v[n] = *(const f32x4*)&cb2q[nt * 128 + wc * 64 + n * 16 + (l4 << 2)];

    // phase A: per-row per-wc-half min
    #pragma unroll
    for (int m = 0; m < 4; m++) {
        float v1 = 3.4e38f;
        #pragma unroll
        for (int n = 0; n < 4; n++)
            #pragma unroll
            for (int r = 0; r < 4; r++)
                v1 = fminf(v1, fmaf(-2.f, acc[n][m][r], c2v[n][r]));
        v1 = fminf(v1, __shfl_xor(v1, 16));
        v1 = fminf(v1, __shfl_xor(v1, 32));
        if (l4 == 0) halfmin[((wr << 6) + (m << 4) + l15) * 2 + wc] = v1;
    }
    __syncthreads();

    // phase B: candidate mask at v1_tile + W (per wc-half, into LDS)
    #pragma unroll
    for (int m = 0; m < 4; m++) {
        int rowl = (wr << 6) + (m << 4) + l15;
        float vt = fminf(halfmin[rowl * 2], halfmin[rowl * 2 + 1]);
        float thrm = vt + W;
        uint blo = 0, bhi = 0;
        #pragma unroll
        for (int n = 0; n < 4; n++)
            #pragma unroll
            for (int r = 0; r < 4; r++) {
                float d = fmaf(-2.f, acc[n][m][r], c2v[n][r]);
                int bit = n * 16 + (l4 << 2) + r;
                if (d < thrm) { if (bit < 32) blo |= 1u << bit; else bhi |= 1u << (bit - 32); }
            }
        blo |= __shfl_xor(blo, 16); bhi |= __shfl_xor(bhi, 16);
        blo |= __shfl_xor(blo, 32); bhi |= __shfl_xor(bhi, 32);
        if (l4 == 0) maskS[rowl * 2 + wc] = make_uint2(blo, bhi);
    }
    __syncthreads();

    // phase C: coalesced per-row write (v1 + 128-bit mask)
    if (t < BMt) {
        float vt = fminf(halfmin[t * 2], halfmin[t * 2 + 1]);
        uint2 a = maskS[t * 2], b = maskS[t * 2 + 1];
        size_t o = (size_t)nt * MM + mt * BMt + t;
        blockv1[o] = vt;
        blockmask[o] = make_uint4(a.x, a.y, b.x, b.y);
    }
}

// ---------------- combine + exact refine + update: ONE WAVE PER ROW, no barriers ----
// Candidate extraction straight from the 128-bit masks (wave-uniform scalar loops);
// eval 4-wide via 16-lane groups; broadcast-merge leaves identical (be,bk) in all
// lanes -> no winner handoff. 4 independent waves/block -> 32 rows in flight/CU.
__global__ __launch_bounds__(256) void crru_kernel(
    const float*  __restrict__ blockv1,
    const uint4*  __restrict__ blockmask,
    const float*  __restrict__ cbq,
    const float*  __restrict__ cb2q,
    float*        __restrict__ resid,
    float*        __restrict__ idx_out,
    short8*       __restrict__ ah,
    int q, float W)
{
    __shared__ float rs[4][DD];          // 8 KB: per-wave resid row
    const int wid  = threadIdx.x >> 6;
    const int lane = threadIdx.x & 63;
    const int row  = blockIdx.x * 4 + wid;
    const int grp  = lane >> 4, gl = lane & 15;

    // classification loads (lanes 0..15), issued early
    float v1 = 3.4e38f;
    uint4 mk = make_uint4(0, 0, 0, 0);
    if (lane < NTILES) {
        size_t o = (size_t)lane * MM + row;
        v1 = blockv1[o];
        mk = blockmask[o];
    }

    // stage resid row into LDS (same-wave RAW: compiler inserts lgkmcnt)
    float* rrow = resid + (size_t)row * DD + lane * 8;
    float4 r0 = *(const float4*)rrow;
    float4 r1 = *(const float4*)(rrow + 4);
    *(float4*)&rs[wid][lane * 8]     = r0;
    *(float4*)&rs[wid][lane * 8 + 4] = r1;

    float g1 = v1;
    #pragma unroll
    for (int off = 32; off >= 1; off >>= 1) g1 = fminf(g1, __shfl_xor(g1, off));
    const float thr = g1 + W;

    unsigned long long act = __ballot((lane < NTILES) && (v1 < thr));

    float be = 3.4e38f; int bk = 0x7FFFFFFF;
    const float* rsw = rs[wid];

    auto eval4 = [&](int k0, int k1, int k2, int k3) {
        int kg = (grp == 0) ? k0 : (grp == 1) ? k1 : (grp == 2) ? k2 : k3;
        float d = 0.f;
        if (kg >= 0) {
            const float* cp = cbq + (size_t)kg * DD + gl * 32;
            const float* rp = rsw + gl * 32;
            #pragma unroll
            for (int j = 0; j < 8; j++) {
                float4 c = *(const float4*)(cp + j * 4);
                float4 r = *(const float4*)(rp + j * 4);
                d = fmaf(r.x, c.x, d); d = fmaf(r.y, c.y, d);
                d = fmaf(r.z, c.z, d); d = fmaf(r.w, c.w, d);
            }
        }
        #pragma unroll
        for (int off = 8; off >= 1; off >>= 1) d += __shfl_xor(d, off);
        #pragma unroll
        for (int g = 0; g < 4; g++) {
            float dg = __shfl(d, g * 16);
            int kg2 = (g == 0) ? k0 : (g == 1) ? k1 : (g == 2) ? k2 : k3;
            if (kg2 >= 0) {
                float e = fmaf(-2.f, dg, cb2q[kg2]);
                if (e < be || (e == be && kg2 < bk)) { be = e; bk = kg2; }
            }
        }
    };

    while (act) {
        int tile = __ffsll(act) - 1; act &= act - 1;
        // broadcast this tile's 128-bit mask (wave-uniform afterwards)
        uint m0 = __shfl((int)mk.x, tile), m1 = __shfl((int)mk.y, tile);
        uint m2 = __shfl((int)mk.z, tile), m3 = __shfl((int)mk.w, tile);
        unsigned long long lo = ((unsigned long long)m1 << 32) | m0;
        unsigned long long hi = ((unsigned long long)m3 << 32) | m2;
        int base = tile * 128;
        while (lo | hi) {
            int c0 = -1, c1 = -1, c2 = -1, c3 = -1;
            #define POP1(dst) \
                if (lo) { int b = __ffsll(lo) - 1; lo &= lo - 1; dst = base + b; } \
                else if (hi) { int b = __ffsll(hi) - 1; hi &= hi - 1; dst = base + 64 + b; }
            POP1(c0) POP1(c1) POP1(c2) POP1(c3)
            #undef POP1
            eval4(c0, c1, c2, c3);
        }
    }
    const int winner = bk;   // identical in all lanes

    if (lane == 0) {
        int b = row >> 11, l = row & (LL - 1);
        idx_out[((size_t)b * QQ + q) * LL + l] = (float)winner;
    }

    const float* cw = cbq + (size_t)winner * DD + lane * 8;
    float4 c0 = *(const float4*)cw;
    float4 c1 = *(const float4*)(cw + 4);
    float4 n0 = make_float4(r0.x - c0.x, r0.y - c0.y, r0.z - c0.z, r0.w - c0.w);
    float4 n1 = make_float4(r1.x - c1.x, r1.y - c1.y, r1.z - c1.z, r1.w - c1.w);
    *(float4*)rrow       = n0;
    *(float4*)(rrow + 4) = n1;

    if (q < QQ - 1) {
        short8 h;
        h[0] = (short)f2bf(n0.x); h[1] = (short)f2bf(n0.y);
        h[2] = (short)f2bf(n0.z); h[3] = (short)f2bf(n0.w);
        h[4] = (short)f2bf(n1.x); h[5] = (short)f2bf(n1.y);
        h[6] = (short)f2bf(n1.z); h[7] = (short)f2bf(n1.w);
        ah[(size_t)row * 64 + lane] = h;   // coalesced 1 KB/row
    }
}

// ---------------- quantized = x - r_final ----------------
__global__ __launch_bounds__(256) void final_kernel(const float* __restrict__ x,
                                                    float* __restrict__ qout) {
    size_t i = (size_t)blockIdx.x * 256 + threadIdx.x;
    float4 xv = ((const float4*)x)[i];
    float4 rv = ((float4*)qout)[i];
    ((float4*)qout)[i] = make_float4(xv.x - rv.x, xv.y - rv.y, xv.z - rv.z, xv.w - rv.w);
}

extern "C" void kernel_launch(void* const* d_in, const int* in_sizes, int n_in,
                              void* d_out, int out_size, void* d_ws, size_t ws_size,
                              hipStream_t stream) {
    (void)in_sizes; (void)n_in; (void)out_size; (void)ws_size;
    const float* x  = (const float*)d_in[0];
    const float* cb = (const float*)d_in[1];
    float* out = (float*)d_out;

    float* idx_out = out;                           // BB*QQ*LL floats
    float* resid   = out + (size_t)BB * QQ * LL;    // doubles as quantized output

    char* w = (char*)d_ws;
    float*  cb2       = (float*)(w);                 // 64 KB
    float*  blockv1   = (float*)(w + 0x10000);       // 1 MB  -> ends 0x110000
    uint4*  blockmask = (uint4*)(w + 0x110000);      // 4 MB  -> ends 0x510000
    short8* ah        = (short8*)(w + 0x510000);     // 16 MB -> ends 0x1510000
    short8* bh        = (short8*)(w + 0x1510000);    // 2 MB  -> ends 0x1710000 (~24 MB)

    cb2_kernel<<<QQ * KK / 4, 256, 0, stream>>>(cb, cb2);
    aprep0_kernel<<<MM / 4, 256, 0, stream>>>(x, resid, ah);

    for (int q = 0; q < QQ; q++) {
        const float* cbq = cb + (size_t)q * KK * DD;
        const float* c2q = cb2 + (size_t)q * KK;
        const float W = 2.0f + 0.3f * q;   // proven coverage window (R7-R9)

        bprep_kernel<<<KK * DD / 8 / 256, 256, 0, stream>>>(cbq, bh);

        gemm_argmin_kernel<<<NTILES * MTILES, 256, 0, stream>>>(ah, bh, c2q,
                                                                blockv1, blockmask, W);

        crru_kernel<<<MM / 4, 256, 0, stream>>>(blockv1, blockmask, cbq, c2q, resid,
                                                idx_out, ah, q, W);
    }

    final_kernel<<<MM * DD / 4 / 256, 256, 0, stream>>>(x, resid);
}

// Round 6
// 558.699 us; speedup vs baseline: 1.4544x; 1.4544x over previous
//
#include <hip/hip_runtime.h>

#define BB 8
#define LL 2048
#define DD 512
#define QQ 8
#define KK 2048
#define MM (BB*LL)      // 16384 points

#define BMt 128         // block tile M (2 wr-waves x 64)
#define BNt 128         // block tile N (2 wc-waves x 64)
#define NSTEPS 16       // DD/32
#define NTILES (KK/BNt) // 16
#define MTILES (MM/BMt) // 128

typedef __attribute__((ext_vector_type(8))) short short8;
typedef __attribute__((ext_vector_type(4))) float f32x4;

#define GLDS(src, dst) __builtin_amdgcn_global_load_lds( \
    (const __attribute__((address_space(1))) void*)(src), \
    (__attribute__((address_space(3))) void*)(dst), 16, 0, 0)

__device__ __forceinline__ ushort f2bf(float f) {
    uint u = __float_as_uint(f);
    u += 0x7FFFu + ((u >> 16) & 1u);
    return (ushort)(u >> 16);
}

// ---------------- cb2: fp32 squared norms ----------------
__global__ __launch_bounds__(256) void cb2_kernel(const float* __restrict__ cb,
                                                  float* __restrict__ cb2) {
    int row  = blockIdx.x * 4 + (threadIdx.x >> 6);
    int lane = threadIdx.x & 63;
    const float* r = cb + (size_t)row * DD + lane * 8;
    float4 a = *(const float4*)r;
    float4 b = *(const float4*)(r + 4);
    float s = a.x*a.x + a.y*a.y + a.z*a.z + a.w*a.w
            + b.x*b.x + b.y*b.y + b.z*b.z + b.w*b.w;
    #pragma unroll
    for (int off = 32; off >= 1; off >>= 1) s += __shfl_xor(s, off);
    if (lane == 0) cb2[row] = s;
}

// ---------------- codebook hi-part, wave-contiguous frag order ----------------
// frag idx = (nt*16+ks)*512 + colblk*64 + kk*16 + colr   (nt: 16 tiles of 128 cols)
__global__ __launch_bounds__(256) void bprep_kernel(const float* __restrict__ cbq,
                                                    short8* __restrict__ bh) {
    int r = blockIdx.x * 256 + threadIdx.x;   // 0..131071, write-coalesced
    int colr   = r & 15;
    int kk     = (r >> 4) & 3;
    int colblk = (r >> 6) & 7;
    int ks     = (r >> 9) & 15;
    int nt     = r >> 13;
    const float* src = cbq + (size_t)(nt * 128 + colblk * 16 + colr) * DD + ks * 32 + kk * 8;
    float f[8];
    *(float4*)&f[0] = *(const float4*)src;
    *(float4*)&f[4] = *(const float4*)(src + 4);
    short8 h8;
    #pragma unroll
    for (int j = 0; j < 8; j++) h8[j] = (short)f2bf(f[j]);
    bh[r] = h8;
}

// ---------------- level-0 A prep: resid <- x, ah <- bf16(x) [row][lane] ----------------
// ah layout: ah[row*64 + j] holds bf16 of resid[row][j*8 .. j*8+8)  (identity: j = d/8)
__global__ __launch_bounds__(256) void aprep0_kernel(const float* __restrict__ x,
                                                     float* __restrict__ resid,
                                                     short8* __restrict__ ah) {
    const int wid  = threadIdx.x >> 6;
    const int lane = threadIdx.x & 63;
    const int row  = blockIdx.x * 4 + wid;
    const float* src = x + (size_t)row * DD + lane * 8;
    float4 v0 = *(const float4*)src;
    float4 v1 = *(const float4*)(src + 4);
    float* dst = resid + (size_t)row * DD + lane * 8;
    *(float4*)dst       = v0;
    *(float4*)(dst + 4) = v1;
    short8 h;
    h[0] = (short)f2bf(v0.x); h[1] = (short)f2bf(v0.y);
    h[2] = (short)f2bf(v0.z); h[3] = (short)f2bf(v0.w);
    h[4] = (short)f2bf(v1.x); h[5] = (short)f2bf(v1.y);
    h[6] = (short)f2bf(v1.z); h[7] = (short)f2bf(v1.w);
    ah[(size_t)row * 64 + lane] = h;
}

// ---------------- 1-term bf16 GEMM + per-tile (v1, candidate bitmask) ----------------
// A+B staged via global_load_lds (32 KB double-buffer). A comes from row-major ah:
// STAGE pre-swizzles the per-lane GLOBAL source chunk (k ^ ((row>>1)&3)) while the
// LDS dest stays linear; the A-frag read applies the same XOR -> each consecutive
// 16-lane batch covers all 8 bank-groups twice = conflict-free (was 8-way in R4).
// Epilogue: tile-min, candidate mask, coalesced phase-C write (from R5).
__global__ __launch_bounds__(256, 4) void gemm_argmin_kernel(
    const short8* __restrict__ ah,
    const short8* __restrict__ bh,
    const float*  __restrict__ cb2q,
    float*        __restrict__ blockv1,    // [NTILES][MM]
    uint4*        __restrict__ blockmask,  // [NTILES][MM]
    float W)
{
    __shared__ short8 smem[2][1024];   // 32 KB: per buf A [0..512), B [512..1024)

    const int id   = blockIdx.x;
    const int xcd  = id & 7;
    const int slot = id >> 3;            // 0..255
    const int nt   = slot & 15;
    const int mt   = xcd * 16 + (slot >> 4);

    const int t    = threadIdx.x;
    const int wid  = t >> 6;
    const int lane = t & 63;
    const int wr   = wid >> 1, wc = wid & 1;
    const int l15  = lane & 15, l4 = lane >> 4;

    // acc[n][m]: codebook-col frag n, point-row frag m (operand-swapped MFMA)
    f32x4 acc[4][4];
    #pragma unroll
    for (int n = 0; n < 4; n++)
        #pragma unroll
        for (int m = 0; m < 4; m++) acc[n][m] = (f32x4){0.f, 0.f, 0.f, 0.f};

    const char* aSrc = (const char*)ah + (size_t)mt * 131072;   // 128 rows x 1 KB
    const char* bSrc = (const char*)bh + (size_t)nt * 131072;

    const int rlo = lane >> 2;                                  // row-in-16
    const int kswb = ((lane & 3) ^ ((rlo >> 1) & 3)) << 4;      // swizzled chunk byte

    auto STAGE = [&](int ks, int buf) {
        char* dst = (char*)&smem[buf][0];
        const char* bs = bSrc + (size_t)ks * 8192;
        #pragma unroll
        for (int j = 0; j < 2; j++) {
            int c = wid * 2 + j;
            GLDS(aSrc + (size_t)(c * 16 + rlo) * 1024 + ks * 64 + kswb,
                 dst + c * 1024);
            GLDS(bs + c * 1024 + lane * 16, dst + 8192 + c * 1024);
        }
    };

    const int aidx = (l15 << 2) + (l4 ^ ((l15 >> 1) & 3));      // swizzled A read

    int buf = 0;
    STAGE(0, 0);

    for (int ks = 0; ks < NSTEPS; ks++) {
        __syncthreads();
        if (ks < NSTEPS - 1) STAGE(ks + 1, buf ^ 1);

        short8 af[4], bf[4];
        #pragma unroll
        for (int m = 0; m < 4; m++)
            af[m] = smem[buf][wr * 256 + m * 64 + aidx];
        #pragma unroll
        for (int n = 0; n < 4; n++)
            bf[n] = smem[buf][512 + wc * 256 + n * 64 + lane];

        #pragma unroll
        for (int n = 0; n < 4; n++)
            #pragma unroll
            for (int m = 0; m < 4; m++)
                acc[n][m] = __builtin_amdgcn_mfma_f32_16x16x32_bf16(bf[n], af[m], acc[n][m], 0, 0, 0);

        buf ^= 1;
    }

    // ---- epilogue ----
    // acc[n][m][r]: row = wr*64 + m*16 + l15 ; col = wc*64 + n*16 + l4*4 + r
    // Last K-step read smem[1]; scratch (3 KB) lives in smem[0], whose last read
    // drained at the ks=15 top barrier -> no barrier needed before phase A.
    float* halfmin = (float*)&smem[0][0];                       // [128][2] floats, 1 KB
    uint2* maskS   = (uint2*)((char*)&smem[0][0] + 1024);       // [128][2] uint2, 2 KB

    f32x4 c2v[4];
    #pragma unroll
    for (int n = 0; n < 4; n++)
        c2v[n] = *(const f32x4*)&cb2q[nt * 128 + wc * 64 + n * 16 + (l4 << 2)];

    // phase A: per-row per-wc-half min
    #pragma unroll
    for (int m = 0; m < 4; m++) {
        float v1 = 3.4e38f;
        #pragma unroll
        for (int n = 0; n < 4; n++)
            #pragma unroll
            for (int r = 0; r < 4; r++)
                v1 = fminf(v1, fmaf(-2.f, acc[n][m][r], c2v[n][r]));
        v1 = fminf(v1, __shfl_xor(v1, 16));
        v1 = fminf(v1, __shfl_xor(v1, 32));
        if (l4 == 0) halfmin[((wr << 6) + (m << 4) + l15) * 2 + wc] = v1;
    }
    __syncthreads();

    // phase B: candidate mask at v1_tile + W (per wc-half, into LDS)
    #pragma unroll
    for (int m = 0; m < 4; m++) {
        int rowl = (wr << 6) + (m << 4) + l15;
        float vt = fminf(halfmin[rowl * 2], halfmin[rowl * 2 + 1]);
        float thrm = vt + W;
        uint blo = 0, bhi = 0;
        #pragma unroll
        for (int n = 0; n < 4; n++)
            #pragma unroll
            for (int r = 0; r < 4; r++) {
                float d = fmaf(-2.f, acc[n][m][r], c2v[n][r]);
                int bit = n * 16 + (l4 << 2) + r;
                if (d < thrm) { if (bit < 32) blo |= 1u << bit; else bhi |= 1u << (bit - 32); }
            }
        blo |= __shfl_xor(blo, 16); bhi |= __shfl_xor(bhi, 16);
        blo |= __shfl_xor(blo, 32); bhi |= __shfl_xor(bhi, 32);
        if (l4 == 0) maskS[rowl * 2 + wc] = make_uint2(blo, bhi);
    }
    __syncthreads();

    // phase C: coalesced per-row write (v1 + 128-bit mask)
    if (t < BMt) {
        float vt = fminf(halfmin[t * 2], halfmin[t * 2 + 1]);
        uint2 a = maskS[t * 2], b = maskS[t * 2 + 1];
        size_t o = (size_t)nt * MM + mt * BMt + t;
        blockv1[o] = vt;
        blockmask[o] = make_uint4(a.x, a.y, b.x, b.y);
    }
}

// ---------------- combine + exact refine + update: ONE WAVE PER ROW, no barriers ----
// Candidate extraction straight from the 128-bit masks (wave-uniform scalar loops);
// eval 4-wide via 16-lane groups; broadcast-merge leaves identical (be,bk) in all
// lanes -> no winner handoff. 4 independent waves/block -> 32 rows in flight/CU.
__global__ __launch_bounds__(256) void crru_kernel(
    const float*  __restrict__ blockv1,
    const uint4*  __restrict__ blockmask,
    const float*  __restrict__ cbq,
    const float*  __restrict__ cb2q,
    float*        __restrict__ resid,
    float*        __restrict__ idx_out,
    short8*       __restrict__ ah,
    int q, float W)
{
    __shared__ float rs[4][DD];          // 8 KB: per-wave resid row
    const int wid  = threadIdx.x >> 6;
    const int lane = threadIdx.x & 63;
    const int row  = blockIdx.x * 4 + wid;
    const int grp  = lane >> 4, gl = lane & 15;

    // classification loads (lanes 0..15), issued early
    float v1 = 3.4e38f;
    uint4 mk = make_uint4(0, 0, 0, 0);
    if (lane < NTILES) {
        size_t o = (size_t)lane * MM + row;
        v1 = blockv1[o];
        mk = blockmask[o];
    }

    // stage resid row into LDS (same-wave RAW: compiler inserts lgkmcnt)
    float* rrow = resid + (size_t)row * DD + lane * 8;
    float4 r0 = *(const float4*)rrow;
    float4 r1 = *(const float4*)(rrow + 4);
    *(float4*)&rs[wid][lane * 8]     = r0;
    *(float4*)&rs[wid][lane * 8 + 4] = r1;

    float g1 = v1;
    #pragma unroll
    for (int off = 32; off >= 1; off >>= 1) g1 = fminf(g1, __shfl_xor(g1, off));
    const float thr = g1 + W;

    unsigned long long act = __ballot((lane < NTILES) && (v1 < thr));

    float be = 3.4e38f; int bk = 0x7FFFFFFF;
    const float* rsw = rs[wid];

    auto eval4 = [&](int k0, int k1, int k2, int k3) {
        int kg = (grp == 0) ? k0 : (grp == 1) ? k1 : (grp == 2) ? k2 : k3;
        float d = 0.f;
        if (kg >= 0) {
            const float* cp = cbq + (size_t)kg * DD + gl * 32;
            const float* rp = rsw + gl * 32;
            #pragma unroll
            for (int j = 0; j < 8; j++) {
                float4 c = *(const float4*)(cp + j * 4);
                float4 r = *(const float4*)(rp + j * 4);
                d = fmaf(r.x, c.x, d); d = fmaf(r.y, c.y, d);
                d = fmaf(r.z, c.z, d); d = fmaf(r.w, c.w, d);
            }
        }
        #pragma unroll
        for (int off = 8; off >= 1; off >>= 1) d += __shfl_xor(d, off);
        #pragma unroll
        for (int g = 0; g < 4; g++) {
            float dg = __shfl(d, g * 16);
            int kg2 = (g == 0) ? k0 : (g == 1) ? k1 : (g == 2) ? k2 : k3;
            if (kg2 >= 0) {
                float e = fmaf(-2.f, dg, cb2q[kg2]);
                if (e < be || (e == be && kg2 < bk)) { be = e; bk = kg2; }
            }
        }
    };

    while (act) {
        int tile = __ffsll(act) - 1; act &= act - 1;
        // broadcast this tile's 128-bit mask (wave-uniform afterwards)
        uint m0 = __shfl((int)mk.x, tile), m1 = __shfl((int)mk.y, tile);
        uint m2 = __shfl((int)mk.z, tile), m3 = __shfl((int)mk.w, tile);
        unsigned long long lo = ((unsigned long long)m1 << 32) | m0;
        unsigned long long hi = ((unsigned long long)m3 << 32) | m2;
        int base = tile * 128;
        while (lo | hi) {
            int c0 = -1, c1 = -1, c2 = -1, c3 = -1;
            #define POP1(dst) \
                if (lo) { int b = __ffsll(lo) - 1; lo &= lo - 1; dst = base + b; } \
                else if (hi) { int b = __ffsll(hi) - 1; hi &= hi - 1; dst = base + 64 + b; }
            POP1(c0) POP1(c1) POP1(c2) POP1(c3)
            #undef POP1
            eval4(c0, c1, c2, c3);
        }
    }
    const int winner = bk;   // identical in all lanes

    if (lane == 0) {
        int b = row >> 11, l = row & (LL - 1);
        idx_out[((size_t)b * QQ + q) * LL + l] = (float)winner;
    }

    const float* cw = cbq + (size_t)winner * DD + lane * 8;
    float4 c0 = *(const float4*)cw;
    float4 c1 = *(const float4*)(cw + 4);
    float4 n0 = make_float4(r0.x - c0.x, r0.y - c0.y, r0.z - c0.z, r0.w - c0.w);
    float4 n1 = make_float4(r1.x - c1.x, r1.y - c1.y, r1.z - c1.z, r1.w - c1.w);
    *(float4*)rrow       = n0;
    *(float4*)(rrow + 4) = n1;

    if (q < QQ - 1) {
        short8 h;
        h[0] = (short)f2bf(n0.x); h[1] = (short)f2bf(n0.y);
        h[2] = (short)f2bf(n0.z); h[3] = (short)f2bf(n0.w);
        h[4] = (short)f2bf(n1.x); h[5] = (short)f2bf(n1.y);
        h[6] = (short)f2bf(n1.z); h[7] = (short)f2bf(n1.w);
        ah[(size_t)row * 64 + lane] = h;   // coalesced 1 KB/row
    }
}

// ---------------- quantized = x - r_final ----------------
__global__ __launch_bounds__(256) void final_kernel(const float* __restrict__ x,
                                                    float* __restrict__ qout) {
    size_t i = (size_t)blockIdx.x * 256 + threadIdx.x;
    float4 xv = ((const float4*)x)[i];
    float4 rv = ((float4*)qout)[i];
    ((float4*)qout)[i] = make_float4(xv.x - rv.x, xv.y - rv.y, xv.z - rv.z, xv.w - rv.w);
}

extern "C" void kernel_launch(void* const* d_in, const int* in_sizes, int n_in,
                              void* d_out, int out_size, void* d_ws, size_t ws_size,
                              hipStream_t stream) {
    (void)in_sizes; (void)n_in; (void)out_size; (void)ws_size;
    const float* x  = (const float*)d_in[0];
    const float* cb = (const float*)d_in[1];
    float* out = (float*)d_out;

    float* idx_out = out;                           // BB*QQ*LL floats
    float* resid   = out + (size_t)BB * QQ * LL;    // doubles as quantized output

    char* w = (char*)d_ws;
    float*  cb2       = (float*)(w);                 // 64 KB
    float*  blockv1   = (float*)(w + 0x10000);       // 1 MB  -> ends 0x110000
    uint4*  blockmask = (uint4*)(w + 0x110000);      // 4 MB  -> ends 0x510000
    short8* ah        = (short8*)(w + 0x510000);     // 16 MB -> ends 0x1510000
    short8* bh        = (short8*)(w + 0x1510000);    // 2 MB  -> ends 0x1710000 (~24 MB)

    cb2_kernel<<<QQ * KK / 4, 256, 0, stream>>>(cb, cb2);
    aprep0_kernel<<<MM / 4, 256, 0, stream>>>(x, resid, ah);

    for (int q = 0; q < QQ; q++) {
        const float* cbq = cb + (size_t)q * KK * DD;
        const float* c2q = cb2 + (size_t)q * KK;
        const float W = 2.0f + 0.3f * q;   // proven coverage window (R7-R9)

        bprep_kernel<<<KK * DD / 8 / 256, 256, 0, stream>>>(cbq, bh);

        gemm_argmin_kernel<<<NTILES * MTILES, 256, 0, stream>>>(ah, bh, c2q,
                                                                blockv1, blockmask, W);

        crru_kernel<<<MM / 4, 256, 0, stream>>>(blockv1, blockmask, cbq, c2q, resid,
                                                idx_out, ah, q, W);
    }

    final_kernel<<<MM * DD / 4 / 256, 256, 0, stream>>>(x, resid);
}

// Round 7
// 523.413 us; speedup vs baseline: 1.5525x; 1.0674x over previous
//
#include <hip/hip_runtime.h>

#define BB 8
#define LL 2048
#define DD 512
#define QQ 8
#define KK 2048
#define MM (BB*LL)      // 16384 points

#define NTILES 16       // 16 col-tiles of 128 (crru interface, unchanged)

typedef __attribute__((ext_vector_type(8))) short short8;
typedef __attribute__((ext_vector_type(4))) float f32x4;

#define GLDS(src, dst) __builtin_amdgcn_global_load_lds( \
    (const __attribute__((address_space(1))) void*)(src), \
    (__attribute__((address_space(3))) void*)(dst), 16, 0, 0)

#define BARX()  asm volatile("s_barrier" ::: "memory")
#define WAIT0() asm volatile("s_waitcnt vmcnt(0)" ::: "memory")

__device__ __forceinline__ ushort f2bf(float f) {
    uint u = __float_as_uint(f);
    u += 0x7FFFu + ((u >> 16) & 1u);
    return (ushort)(u >> 16);
}

// ---------------- cb2: fp32 squared norms ----------------
__global__ __launch_bounds__(256) void cb2_kernel(const float* __restrict__ cb,
                                                  float* __restrict__ cb2) {
    int row  = blockIdx.x * 4 + (threadIdx.x >> 6);
    int lane = threadIdx.x & 63;
    const float* r = cb + (size_t)row * DD + lane * 8;
    float4 a = *(const float4*)r;
    float4 b = *(const float4*)(r + 4);
    float s = a.x*a.x + a.y*a.y + a.z*a.z + a.w*a.w
            + b.x*b.x + b.y*b.y + b.z*b.z + b.w*b.w;
    #pragma unroll
    for (int off = 32; off >= 1; off >>= 1) s += __shfl_xor(s, off);
    if (lane == 0) cb2[row] = s;
}

// ---------------- B prep: bh2[col*64 + j] = bf16 of cbq[col][j*8..j*8+8) ----------------
// identical layout to ah ([row][16B chunk], 1 KB per row) -> same staging machinery
__global__ __launch_bounds__(256) void bprep_kernel(const float* __restrict__ cbq,
                                                    short8* __restrict__ bh2) {
    const int wid  = threadIdx.x >> 6;
    const int lane = threadIdx.x & 63;
    const int col  = blockIdx.x * 4 + wid;
    const float* src = cbq + (size_t)col * DD + lane * 8;
    float4 v0 = *(const float4*)src;
    float4 v1 = *(const float4*)(src + 4);
    short8 h;
    h[0] = (short)f2bf(v0.x); h[1] = (short)f2bf(v0.y);
    h[2] = (short)f2bf(v0.z); h[3] = (short)f2bf(v0.w);
    h[4] = (short)f2bf(v1.x); h[5] = (short)f2bf(v1.y);
    h[6] = (short)f2bf(v1.z); h[7] = (short)f2bf(v1.w);
    bh2[(size_t)col * 64 + lane] = h;
}

// ---------------- level-0 A prep: resid <- x, ah <- bf16(x) [row][lane] ----------------
__global__ __launch_bounds__(256) void aprep0_kernel(const float* __restrict__ x,
                                                     float* __restrict__ resid,
                                                     short8* __restrict__ ah) {
    const int wid  = threadIdx.x >> 6;
    const int lane = threadIdx.x & 63;
    const int row  = blockIdx.x * 4 + wid;
    const float* src = x + (size_t)row * DD + lane * 8;
    float4 v0 = *(const float4*)src;
    float4 v1 = *(const float4*)(src + 4);
    float* dst = resid + (size_t)row * DD + lane * 8;
    *(float4*)dst       = v0;
    *(float4*)(dst + 4) = v1;
    short8 h;
    h[0] = (short)f2bf(v0.x); h[1] = (short)f2bf(v0.y);
    h[2] = (short)f2bf(v0.z); h[3] = (short)f2bf(v0.w);
    h[4] = (short)f2bf(v1.x); h[5] = (short)f2bf(v1.y);
    h[6] = (short)f2bf(v1.z); h[7] = (short)f2bf(v1.w);
    ah[(size_t)row * 64 + lane] = h;
}

// ---------------- 256x256 deep-pipelined bf16 GEMM + per-tile (v1, mask) ----------------
// 512 blocks x 512 thr (8 waves, 2M x 4N; wave tile 128x64). BK=64, 8 K-tiles.
// 128 KB LDS double-buffer, global_load_lds staging with mod-8 XOR swizzle
// (pre-swizzled global source, swizzled ds_read; LDS dest linear - r6-proven pattern).
// Per K-tile: 4 MFMA phases (16 MFMA each) split by raw s_barrier; next tile's
// 8 loads issued in phases 0-1; single vmcnt(0) at tile boundary (2-3 phases slack).
// Accumulation order K-ascending == r6 -> approx distances bit-identical.
__global__ __launch_bounds__(512, 2) void gemm_argmin_kernel(
    const short8* __restrict__ ah,
    const short8* __restrict__ bh2,
    const float*  __restrict__ cb2q,
    float*        __restrict__ blockv1,    // [NTILES][MM]
    uint4*        __restrict__ blockmask,  // [NTILES][MM]
    float W)
{
    __shared__ char smemc[131072];   // [2 buf][A 32KB | B 32KB]

    const int id  = blockIdx.x;
    const int xcd = id & 7;
    const int s   = id >> 3;          // 0..63
    const int nt  = s & 7;            // 0..7 (256-col tiles)
    const int mt  = xcd * 8 + (s >> 3);  // 0..63 (256-row tiles), A reuse per XCD

    const int tid  = threadIdx.x;
    const int wid  = tid >> 6;
    const int lane = tid & 63;
    const int wr   = wid >> 2;        // 0..1 : rows [wr*128, +128)
    const int wcn  = wid & 3;         // 0..3 : cols [wcn*64, +64)
    const int l15  = lane & 15, l4 = lane >> 4;

    // acc[n][m]: row = wr*128 + m*16 + l15 ; col = wcn*64 + n*16 + l4*4 + r
    f32x4 acc[4][8];
    #pragma unroll
    for (int n = 0; n < 4; n++)
        #pragma unroll
        for (int m = 0; m < 8; m++) acc[n][m] = (f32x4){0.f, 0.f, 0.f, 0.f};

    const char* aSrc = (const char*)ah  + ((size_t)mt << 18);   // 256 rows x 1 KB
    const char* bSrc = (const char*)bh2 + ((size_t)nt << 18);

    // stage quarter p (64 rows of A + 64 cols of B) of K-tile tt into buffer bufn.
    // dest chunk g = p*512 + tid: rL = g>>3, slot = g&7 holds src chunk slot^(rL&7).
    // GLDS dest is WAVE-UNIFORM base (HW appends lane*16); source is per-lane.
    #define STAGEQ(tt, bufn, p) do { \
        int g_ = (p) * 512 + tid; \
        int rL_ = g_ >> 3, st_ = g_ & 7; \
        int k_ = st_ ^ (rL_ & 7); \
        char* db_ = smemc + (bufn) * 65536 + ((p) * 512 + wid * 64) * 16; \
        GLDS(aSrc + (size_t)rL_ * 1024 + (tt) * 128 + k_ * 16, db_); \
        GLDS(bSrc + (size_t)rL_ * 1024 + (tt) * 128 + k_ * 16, db_ + 32768); \
    } while (0)

    short8 af[4][2], bf[4][2];   // af: current m-half; bf: all 4 n-frags

    #define LDA(mh) do { \
        _Pragma("unroll") for (int mm = 0; mm < 4; mm++) \
        _Pragma("unroll") for (int ks = 0; ks < 2; ks++) { \
            int rL_ = wr * 128 + ((mh) * 4 + mm) * 16 + l15; \
            int c_ = ks * 4 + l4; \
            af[mm][ks] = *(const short8*)(smemc + ab + rL_ * 128 + ((c_ ^ (rL_ & 7)) << 4)); \
        } } while (0)

    #define LDB(nh) do { \
        _Pragma("unroll") for (int nn = 0; nn < 2; nn++) \
        _Pragma("unroll") for (int ks = 0; ks < 2; ks++) { \
            int cL_ = wcn * 64 + ((nh) * 2 + nn) * 16 + l15; \
            int c_ = ks * 4 + l4; \
            bf[(nh)*2+nn][ks] = *(const short8*)(smemc + ab + 32768 + cL_ * 128 + ((c_ ^ (cL_ & 7)) << 4)); \
        } } while (0)

    #define PH(mh, nh) do { \
        __builtin_amdgcn_s_setprio(1); \
        _Pragma("unroll") for (int nn = 0; nn < 2; nn++) \
        _Pragma("unroll") for (int mm = 0; mm < 4; mm++) \
        _Pragma("unroll") for (int ks = 0; ks < 2; ks++) \
            acc[(nh)*2+nn][(mh)*4+mm] = __builtin_amdgcn_mfma_f32_16x16x32_bf16( \
                bf[(nh)*2+nn][ks], af[mm][ks], acc[(nh)*2+nn][(mh)*4+mm], 0, 0, 0); \
        __builtin_amdgcn_s_setprio(0); \
    } while (0)

    // prologue: stage K-tile 0 fully, drain, barrier
    STAGEQ(0, 0, 0); STAGEQ(0, 0, 1); STAGEQ(0, 0, 2); STAGEQ(0, 0, 3);
    WAIT0();
    BARX();

    for (int t = 0; t < 8; t++) {
        const uint ab = (uint)(t & 1) * 65536u;
        const int nbuf = (t & 1) ^ 1;
        // phase 0: (m-half 0, n-half 0)
        LDA(0); LDB(0);
        if (t < 7) { STAGEQ(t + 1, nbuf, 0); STAGEQ(t + 1, nbuf, 1); }
        PH(0, 0);
        BARX();
        // phase 1: (0, 1)
        LDB(1);
        if (t < 7) { STAGEQ(t + 1, nbuf, 2); STAGEQ(t + 1, nbuf, 3); }
        PH(0, 1);
        BARX();
        // phase 2: (1, 0)
        LDA(1);
        PH(1, 0);
        BARX();
        // phase 3: (1, 1); tile boundary: drain next tile's 8 loads, barrier
        PH(1, 1);
        if (t < 7) WAIT0();
        BARX();
    }

    // ---- epilogue: per-row tile-min + candidate masks for TWO 128-col tiles ----
    // scratch in buf0 A region (t=7 read only buf1; per-phase barriers kept all
    // waves lockstep -> no wave still reads buf0)
    float* halfmin = (float*)smemc;             // [256][4 wcn]  4 KB
    uint2* maskS   = (uint2*)(smemc + 4096);    // [256][4 wcn]  8 KB

    f32x4 c2v[4];
    #pragma unroll
    for (int n = 0; n < 4; n++)
        c2v[n] = *(const f32x4*)&cb2q[nt * 256 + wcn * 64 + n * 16 + (l4 << 2)];

    // phase A: per-row min over this wave's 64 cols
    #pragma unroll
    for (int m = 0; m < 8; m++) {
        float v = 3.4e38f;
        #pragma unroll
        for (int n = 0; n < 4; n++)
            #pragma unroll
            for (int r = 0; r < 4; r++)
                v = fminf(v, fmaf(-2.f, acc[n][m][r], c2v[n][r]));
        v = fminf(v, __shfl_xor(v, 16));
        v = fminf(v, __shfl_xor(v, 32));
        if (l4 == 0) halfmin[(wr * 128 + m * 16 + l15) * 4 + wcn] = v;
    }
    __syncthreads();

    // phase B: candidate mask at v1_tile + W (tile = wcn pair)
    #pragma unroll
    for (int m = 0; m < 8; m++) {
        int rL = wr * 128 + m * 16 + l15;
        int pb = wcn & 2;
        float vt = fminf(halfmin[rL * 4 + pb], halfmin[rL * 4 + pb + 1]);
        float thrm = vt + W;
        uint blo = 0, bhi = 0;
        #pragma unroll
        for (int n = 0; n < 4; n++)
            #pragma unroll
            for (int r = 0; r < 4; r++) {
                float d = fmaf(-2.f, acc[n][m][r], c2v[n][r]);
                int bit = n * 16 + (l4 << 2) + r;
                if (d < thrm) { if (bit < 32) blo |= 1u << bit; else bhi |= 1u << (bit - 32); }
            }
        blo |= __shfl_xor(blo, 16); bhi |= __shfl_xor(bhi, 16);
        blo |= __shfl_xor(blo, 32); bhi |= __shfl_xor(bhi, 32);
        if (l4 == 0) maskS[rL * 4 + wcn] = make_uint2(blo, bhi);
    }
    __syncthreads();

    // phase C: coalesced write, tid -> (T = tile half, rL = row)
    {
        int T = tid >> 8, rL = tid & 255;
        float vt = fminf(halfmin[rL * 4 + T * 2], halfmin[rL * 4 + T * 2 + 1]);
        uint2 lo = maskS[rL * 4 + T * 2], hi = maskS[rL * 4 + T * 2 + 1];
        size_t o = (size_t)(nt * 2 + T) * MM + mt * 256 + rL;
        blockv1[o] = vt;
        blockmask[o] = make_uint4(lo.x, lo.y, hi.x, hi.y);
    }
    #undef STAGEQ
    #undef LDA
    #undef LDB
    #undef PH
}

// ---------------- combine + exact refine + update: ONE WAVE PER ROW, no barriers ----
__global__ __launch_bounds__(256) void crru_kernel(
    const float*  __restrict__ blockv1,
    const uint4*  __restrict__ blockmask,
    const float*  __restrict__ cbq,
    const float*  __restrict__ cb2q,
    float*        __restrict__ resid,
    float*        __restrict__ idx_out,
    short8*       __restrict__ ah,
    int q, float W)
{
    __shared__ float rs[4][DD];          // 8 KB: per-wave resid row
    const int wid  = threadIdx.x >> 6;
    const int lane = threadIdx.x & 63;
    const int row  = blockIdx.x * 4 + wid;
    const int grp  = lane >> 4, gl = lane & 15;

    float v1 = 3.4e38f;
    uint4 mk = make_uint4(0, 0, 0, 0);
    if (lane < NTILES) {
        size_t o = (size_t)lane * MM + row;
        v1 = blockv1[o];
        mk = blockmask[o];
    }

    float* rrow = resid + (size_t)row * DD + lane * 8;
    float4 r0 = *(const float4*)rrow;
    float4 r1 = *(const float4*)(rrow + 4);
    *(float4*)&rs[wid][lane * 8]     = r0;
    *(float4*)&rs[wid][lane * 8 + 4] = r1;

    float g1 = v1;
    #pragma unroll
    for (int off = 32; off >= 1; off >>= 1) g1 = fminf(g1, __shfl_xor(g1, off));
    const float thr = g1 + W;

    unsigned long long act = __ballot((lane < NTILES) && (v1 < thr));

    float be = 3.4e38f; int bk = 0x7FFFFFFF;
    const float* rsw = rs[wid];

    auto eval4 = [&](int k0, int k1, int k2, int k3) {
        int kg = (grp == 0) ? k0 : (grp == 1) ? k1 : (grp == 2) ? k2 : k3;
        float d = 0.f;
        if (kg >= 0) {
            const float* cp = cbq + (size_t)kg * DD + gl * 32;
            const float* rp = rsw + gl * 32;
            #pragma unroll
            for (int j = 0; j < 8; j++) {
                float4 c = *(const float4*)(cp + j * 4);
                float4 r = *(const float4*)(rp + j * 4);
                d = fmaf(r.x, c.x, d); d = fmaf(r.y, c.y, d);
                d = fmaf(r.z, c.z, d); d = fmaf(r.w, c.w, d);
            }
        }
        #pragma unroll
        for (int off = 8; off >= 1; off >>= 1) d += __shfl_xor(d, off);
        #pragma unroll
        for (int g = 0; g < 4; g++) {
            float dg = __shfl(d, g * 16);
            int kg2 = (g == 0) ? k0 : (g == 1) ? k1 : (g == 2) ? k2 : k3;
            if (kg2 >= 0) {
                float e = fmaf(-2.f, dg, cb2q[kg2]);
                if (e < be || (e == be && kg2 < bk)) { be = e; bk = kg2; }
            }
        }
    };

    while (act) {
        int tile = __ffsll(act) - 1; act &= act - 1;
        uint m0 = __shfl((int)mk.x, tile), m1 = __shfl((int)mk.y, tile);
        uint m2 = __shfl((int)mk.z, tile), m3 = __shfl((int)mk.w, tile);
        unsigned long long lo = ((unsigned long long)m1 << 32) | m0;
        unsigned long long hi = ((unsigned long long)m3 << 32) | m2;
        int base = tile * 128;
        while (lo | hi) {
            int c0 = -1, c1 = -1, c2 = -1, c3 = -1;
            #define POP1(dst) \
                if (lo) { int b = __ffsll(lo) - 1; lo &= lo - 1; dst = base + b; } \
                else if (hi) { int b = __ffsll(hi) - 1; hi &= hi - 1; dst = base + 64 + b; }
            POP1(c0) POP1(c1) POP1(c2) POP1(c3)
            #undef POP1
            eval4(c0, c1, c2, c3);
        }
    }
    const int winner = bk;   // identical in all lanes

    if (lane == 0) {
        int b = row >> 11, l = row & (LL - 1);
        idx_out[((size_t)b * QQ + q) * LL + l] = (float)winner;
    }

    const float* cw = cbq + (size_t)winner * DD + lane * 8;
    float4 c0 = *(const float4*)cw;
    float4 c1 = *(const float4*)(cw + 4);
    float4 n0 = make_float4(r0.x - c0.x, r0.y - c0.y, r0.z - c0.z, r0.w - c0.w);
    float4 n1 = make_float4(r1.x - c1.x, r1.y - c1.y, r1.z - c1.z, r1.w - c1.w);
    *(float4*)rrow       = n0;
    *(float4*)(rrow + 4) = n1;

    if (q < QQ - 1) {
        short8 h;
        h[0] = (short)f2bf(n0.x); h[1] = (short)f2bf(n0.y);
        h[2] = (short)f2bf(n0.z); h[3] = (short)f2bf(n0.w);
        h[4] = (short)f2bf(n1.x); h[5] = (short)f2bf(n1.y);
        h[6] = (short)f2bf(n1.z); h[7] = (short)f2bf(n1.w);
        ah[(size_t)row * 64 + lane] = h;   // coalesced 1 KB/row
    }
}

// ---------------- quantized = x - r_final ----------------
__global__ __launch_bounds__(256) void final_kernel(const float* __restrict__ x,
                                                    float* __restrict__ qout) {
    size_t i = (size_t)blockIdx.x * 256 + threadIdx.x;
    float4 xv = ((const float4*)x)[i];
    float4 rv = ((float4*)qout)[i];
    ((float4*)qout)[i] = make_float4(xv.x - rv.x, xv.y - rv.y, xv.z - rv.z, xv.w - rv.w);
}

extern "C" void kernel_launch(void* const* d_in, const int* in_sizes, int n_in,
                              void* d_out, int out_size, void* d_ws, size_t ws_size,
                              hipStream_t stream) {
    (void)in_sizes; (void)n_in; (void)out_size; (void)ws_size;
    const float* x  = (const float*)d_in[0];
    const float* cb = (const float*)d_in[1];
    float* out = (float*)d_out;

    float* idx_out = out;                           // BB*QQ*LL floats
    float* resid   = out + (size_t)BB * QQ * LL;    // doubles as quantized output

    char* w = (char*)d_ws;
    float*  cb2       = (float*)(w);                 // 64 KB
    float*  blockv1   = (float*)(w + 0x10000);       // 1 MB  -> ends 0x110000
    uint4*  blockmask = (uint4*)(w + 0x110000);      // 4 MB  -> ends 0x510000
    short8* ah        = (short8*)(w + 0x510000);     // 16 MB -> ends 0x1510000
    short8* bh2       = (short8*)(w + 0x1510000);    // 2 MB  -> ends 0x1710000 (~24 MB)

    cb2_kernel<<<QQ * KK / 4, 256, 0, stream>>>(cb, cb2);
    aprep0_kernel<<<MM / 4, 256, 0, stream>>>(x, resid, ah);

    for (int q = 0; q < QQ; q++) {
        const float* cbq = cb + (size_t)q * KK * DD;
        const float* c2q = cb2 + (size_t)q * KK;
        const float W = 2.0f + 0.3f * q;   // proven coverage window (R7-R9)

        bprep_kernel<<<KK / 4, 256, 0, stream>>>(cbq, bh2);

        gemm_argmin_kernel<<<512, 512, 0, stream>>>(ah, bh2, c2q,
                                                    blockv1, blockmask, W);

        crru_kernel<<<MM / 4, 256, 0, stream>>>(blockv1, blockmask, cbq, c2q, resid,
                                                idx_out, ah, q, W);
    }

    final_kernel<<<MM * DD / 4 / 256, 256, 0, stream>>>(x, resid);
}

// Round 8
// 517.113 us; speedup vs baseline: 1.5714x; 1.0122x over previous
//
#include <hip/hip_runtime.h>

#define BB 8
#define LL 2048
#define DD 512
#define QQ 8
#define KK 2048
#define MM (BB*LL)      // 16384 points

#define NTILES 16       // 16 col-tiles of 128 (crru interface, unchanged)

typedef __attribute__((ext_vector_type(8))) short short8;
typedef __attribute__((ext_vector_type(4))) float f32x4;

#define GLDS(src, dst) __builtin_amdgcn_global_load_lds( \
    (const __attribute__((address_space(1))) void*)(src), \
    (__attribute__((address_space(3))) void*)(dst), 16, 0, 0)

#define BARX()  asm volatile("s_barrier" ::: "memory")
#define WAIT0() asm volatile("s_waitcnt vmcnt(0)" ::: "memory")

__device__ __forceinline__ ushort f2bf(float f) {
    uint u = __float_as_uint(f);
    u += 0x7FFFu + ((u >> 16) & 1u);
    return (ushort)(u >> 16);
}

// ---------------- cb2: fp32 squared norms ----------------
__global__ __launch_bounds__(256) void cb2_kernel(const float* __restrict__ cb,
                                                  float* __restrict__ cb2) {
    int row  = blockIdx.x * 4 + (threadIdx.x >> 6);
    int lane = threadIdx.x & 63;
    const float* r = cb + (size_t)row * DD + lane * 8;
    float4 a = *(const float4*)r;
    float4 b = *(const float4*)(r + 4);
    float s = a.x*a.x + a.y*a.y + a.z*a.z + a.w*a.w
            + b.x*b.x + b.y*b.y + b.z*b.z + b.w*b.w;
    #pragma unroll
    for (int off = 32; off >= 1; off >>= 1) s += __shfl_xor(s, off);
    if (lane == 0) cb2[row] = s;
}

// ---------------- B prep: bh2[col*64 + j] = bf16 of cbq[col][j*8..j*8+8) ----------------
__global__ __launch_bounds__(256) void bprep_kernel(const float* __restrict__ cbq,
                                                    short8* __restrict__ bh2) {
    const int wid  = threadIdx.x >> 6;
    const int lane = threadIdx.x & 63;
    const int col  = blockIdx.x * 4 + wid;
    const float* src = cbq + (size_t)col * DD + lane * 8;
    float4 v0 = *(const float4*)src;
    float4 v1 = *(const float4*)(src + 4);
    short8 h;
    h[0] = (short)f2bf(v0.x); h[1] = (short)f2bf(v0.y);
    h[2] = (short)f2bf(v0.z); h[3] = (short)f2bf(v0.w);
    h[4] = (short)f2bf(v1.x); h[5] = (short)f2bf(v1.y);
    h[6] = (short)f2bf(v1.z); h[7] = (short)f2bf(v1.w);
    bh2[(size_t)col * 64 + lane] = h;
}

// ---------------- level-0 A prep: resid <- x, ah <- bf16(x) [row][lane] ----------------
__global__ __launch_bounds__(256) void aprep0_kernel(const float* __restrict__ x,
                                                     float* __restrict__ resid,
                                                     short8* __restrict__ ah) {
    const int wid  = threadIdx.x >> 6;
    const int lane = threadIdx.x & 63;
    const int row  = blockIdx.x * 4 + wid;
    const float* src = x + (size_t)row * DD + lane * 8;
    float4 v0 = *(const float4*)src;
    float4 v1 = *(const float4*)(src + 4);
    float* dst = resid + (size_t)row * DD + lane * 8;
    *(float4*)dst       = v0;
    *(float4*)(dst + 4) = v1;
    short8 h;
    h[0] = (short)f2bf(v0.x); h[1] = (short)f2bf(v0.y);
    h[2] = (short)f2bf(v0.z); h[3] = (short)f2bf(v0.w);
    h[4] = (short)f2bf(v1.x); h[5] = (short)f2bf(v1.y);
    h[6] = (short)f2bf(v1.z); h[7] = (short)f2bf(v1.w);
    ah[(size_t)row * 64 + lane] = h;
}

// ---------------- 256x256 BK=64 bf16 GEMM + per-tile (v1, mask) ----------------
// 512 blocks x 512 thr (8 waves 2Mx4N, wave tile 128x64), 8 K-tiles.
// ONE barrier-pair per K-tile: the tile body {8 GLDS for t+1; 24 ds_reads;
// 64 MFMA} is a single compiler-scheduled block (fine lgkmcnt, m97-proven);
// boundary = vmcnt(0)+s_barrier, with ~400cy of MFMA slack to hide the loads.
// XOR-swizzled staging (pre-swizzled global src, swizzled ds_read) from r6/r7.
// Accumulation order K-ascending == r6/r7 -> approx distances bit-identical.
__global__ __launch_bounds__(512, 2) void gemm_argmin_kernel(
    const short8* __restrict__ ah,
    const short8* __restrict__ bh2,
    const float*  __restrict__ cb2q,
    float*        __restrict__ blockv1,    // [NTILES][MM]
    uint4*        __restrict__ blockmask,  // [NTILES][MM]
    float W)
{
    __shared__ char smemc[131072];   // [2 buf][A 32KB | B 32KB]

    const int id  = blockIdx.x;
    const int xcd = id & 7;
    const int s   = id >> 3;             // 0..63
    const int nt  = s & 7;               // 0..7 (256-col tiles)
    const int mt  = xcd * 8 + (s >> 3);  // 0..63 (256-row tiles), A reuse per XCD

    const int tid  = threadIdx.x;
    const int wid  = tid >> 6;
    const int lane = tid & 63;
    const int wr   = wid >> 2;           // rows [wr*128, +128)
    const int wcn  = wid & 3;            // cols [wcn*64, +64)
    const int l15  = lane & 15, l4 = lane >> 4;

    // acc[n][m]: row = wr*128 + m*16 + l15 ; col = wcn*64 + n*16 + l4*4 + r
    f32x4 acc[4][8];
    #pragma unroll
    for (int n = 0; n < 4; n++)
        #pragma unroll
        for (int m = 0; m < 8; m++) acc[n][m] = (f32x4){0.f, 0.f, 0.f, 0.f};

    const char* aSrc = (const char*)ah  + ((size_t)mt << 18);   // 256 rows x 1 KB
    const char* bSrc = (const char*)bh2 + ((size_t)nt << 18);

    // stage quarter p of K-tile tt into buffer bufn (r7-verified indexing):
    // dest chunk g = p*512+tid (linear); slot g&7 of row g>>3 holds src chunk (g&7)^(row&7)
    #define STAGEQ(tt, bufn, p) do { \
        int g_ = (p) * 512 + tid; \
        int rL_ = g_ >> 3, st_ = g_ & 7; \
        int k_ = st_ ^ (rL_ & 7); \
        char* db_ = smemc + (bufn) * 65536 + ((p) * 512 + wid * 64) * 16; \
        GLDS(aSrc + (size_t)rL_ * 1024 + (tt) * 128 + k_ * 16, db_); \
        GLDS(bSrc + (size_t)rL_ * 1024 + (tt) * 128 + k_ * 16, db_ + 32768); \
    } while (0)

    short8 af[4][2], bf[4][2];

    #define LDA(mh) do { \
        _Pragma("unroll") for (int mm = 0; mm < 4; mm++) \
        _Pragma("unroll") for (int ks = 0; ks < 2; ks++) { \
            int rL_ = wr * 128 + ((mh) * 4 + mm) * 16 + l15; \
            int c_ = ks * 4 + l4; \
            af[mm][ks] = *(const short8*)(smemc + ab + rL_ * 128 + ((c_ ^ (rL_ & 7)) << 4)); \
        } } while (0)

    #define LDBALL() do { \
        _Pragma("unroll") for (int nn = 0; nn < 4; nn++) \
        _Pragma("unroll") for (int ks = 0; ks < 2; ks++) { \
            int cL_ = wcn * 64 + nn * 16 + l15; \
            int c_ = ks * 4 + l4; \
            bf[nn][ks] = *(const short8*)(smemc + ab + 32768 + cL_ * 128 + ((c_ ^ (cL_ & 7)) << 4)); \
        } } while (0)

    // 32 MFMA for m-half mh: ks outermost (32 independent MFMAs between dep pairs),
    // per-element K order ks=0,1 ascending (bit-identical accumulation)
    #define PH(mh) do { \
        __builtin_amdgcn_s_setprio(1); \
        _Pragma("unroll") for (int ks = 0; ks < 2; ks++) \
        _Pragma("unroll") for (int nn = 0; nn < 4; nn++) \
        _Pragma("unroll") for (int mm = 0; mm < 4; mm++) \
            acc[nn][(mh)*4+mm] = __builtin_amdgcn_mfma_f32_16x16x32_bf16( \
                bf[nn][ks], af[mm][ks], acc[nn][(mh)*4+mm], 0, 0, 0); \
        __builtin_amdgcn_s_setprio(0); \
    } while (0)

    // prologue: stage K-tile 0, drain, barrier
    STAGEQ(0, 0, 0); STAGEQ(0, 0, 1); STAGEQ(0, 0, 2); STAGEQ(0, 0, 3);
    WAIT0();
    BARX();

    for (int t = 0; t < 8; t++) {
        const uint ab = (uint)(t & 1) * 65536u;
        const int nbuf = (t & 1) ^ 1;
        if (t < 7) { STAGEQ(t + 1, nbuf, 0); STAGEQ(t + 1, nbuf, 1);
                     STAGEQ(t + 1, nbuf, 2); STAGEQ(t + 1, nbuf, 3); }
        LDBALL();
        LDA(0);
        PH(0);
        LDA(1);
        PH(1);
        if (t < 7) WAIT0();
        BARX();
    }

    // ---- epilogue: per-row tile-min + candidate masks for TWO 128-col tiles ----
    float* halfmin = (float*)smemc;             // [256][4 wcn]  4 KB (buf0 region)
    uint2* maskS   = (uint2*)(smemc + 4096);    // [256][4 wcn]  8 KB

    f32x4 c2v[4];
    #pragma unroll
    for (int n = 0; n < 4; n++)
        c2v[n] = *(const f32x4*)&cb2q[nt * 256 + wcn * 64 + n * 16 + (l4 << 2)];

    #pragma unroll
    for (int m = 0; m < 8; m++) {
        float v = 3.4e38f;
        #pragma unroll
        for (int n = 0; n < 4; n++)
            #pragma unroll
            for (int r = 0; r < 4; r++)
                v = fminf(v, fmaf(-2.f, acc[n][m][r], c2v[n][r]));
        v = fminf(v, __shfl_xor(v, 16));
        v = fminf(v, __shfl_xor(v, 32));
        if (l4 == 0) halfmin[(wr * 128 + m * 16 + l15) * 4 + wcn] = v;
    }
    __syncthreads();

    #pragma unroll
    for (int m = 0; m < 8; m++) {
        int rL = wr * 128 + m * 16 + l15;
        int pb = wcn & 2;
        float vt = fminf(halfmin[rL * 4 + pb], halfmin[rL * 4 + pb + 1]);
        float thrm = vt + W;
        uint blo = 0, bhi = 0;
        #pragma unroll
        for (int n = 0; n < 4; n++)
            #pragma unroll
            for (int r = 0; r < 4; r++) {
                float d = fmaf(-2.f, acc[n][m][r], c2v[n][r]);
                int bit = n * 16 + (l4 << 2) + r;
                if (d < thrm) { if (bit < 32) blo |= 1u << bit; else bhi |= 1u << (bit - 32); }
            }
        blo |= __shfl_xor(blo, 16); bhi |= __shfl_xor(bhi, 16);
        blo |= __shfl_xor(blo, 32); bhi |= __shfl_xor(bhi, 32);
        if (l4 == 0) maskS[rL * 4 + wcn] = make_uint2(blo, bhi);
    }
    __syncthreads();

    {
        int T = tid >> 8, rL = tid & 255;
        float vt = fminf(halfmin[rL * 4 + T * 2], halfmin[rL * 4 + T * 2 + 1]);
        uint2 lo = maskS[rL * 4 + T * 2], hi = maskS[rL * 4 + T * 2 + 1];
        size_t o = (size_t)(nt * 2 + T) * MM + mt * 256 + rL;
        blockv1[o] = vt;
        blockmask[o] = make_uint4(lo.x, lo.y, hi.x, hi.y);
    }
    #undef STAGEQ
    #undef LDA
    #undef LDBALL
    #undef PH
}

// ---------------- combine + exact refine + update: ONE WAVE PER ROW, no barriers ----
// At q==QQ-1: writes quantized = x - new_resid directly (final_kernel fused away).
__global__ __launch_bounds__(256) void crru_kernel(
    const float*  __restrict__ blockv1,
    const uint4*  __restrict__ blockmask,
    const float*  __restrict__ cbq,
    const float*  __restrict__ cb2q,
    const float*  __restrict__ xin,
    float*        __restrict__ resid,
    float*        __restrict__ idx_out,
    short8*       __restrict__ ah,
    int q, float W)
{
    __shared__ float rs[4][DD];          // 8 KB: per-wave resid row
    const int wid  = threadIdx.x >> 6;
    const int lane = threadIdx.x & 63;
    const int row  = blockIdx.x * 4 + wid;
    const int grp  = lane >> 4, gl = lane & 15;

    float v1 = 3.4e38f;
    uint4 mk = make_uint4(0, 0, 0, 0);
    if (lane < NTILES) {
        size_t o = (size_t)lane * MM + row;
        v1 = blockv1[o];
        mk = blockmask[o];
    }

    float* rrow = resid + (size_t)row * DD + lane * 8;
    float4 r0 = *(const float4*)rrow;
    float4 r1 = *(const float4*)(rrow + 4);
    *(float4*)&rs[wid][lane * 8]     = r0;
    *(float4*)&rs[wid][lane * 8 + 4] = r1;

    float g1 = v1;
    #pragma unroll
    for (int off = 32; off >= 1; off >>= 1) g1 = fminf(g1, __shfl_xor(g1, off));
    const float thr = g1 + W;

    unsigned long long act = __ballot((lane < NTILES) && (v1 < thr));

    float be = 3.4e38f; int bk = 0x7FFFFFFF;
    const float* rsw = rs[wid];

    auto eval4 = [&](int k0, int k1, int k2, int k3) {
        int kg = (grp == 0) ? k0 : (grp == 1) ? k1 : (grp == 2) ? k2 : k3;
        float d = 0.f;
        if (kg >= 0) {
            const float* cp = cbq + (size_t)kg * DD + gl * 32;
            const float* rp = rsw + gl * 32;
            #pragma unroll
            for (int j = 0; j < 8; j++) {
                float4 c = *(const float4*)(cp + j * 4);
                float4 r = *(const float4*)(rp + j * 4);
                d = fmaf(r.x, c.x, d); d = fmaf(r.y, c.y, d);
                d = fmaf(r.z, c.z, d); d = fmaf(r.w, c.w, d);
            }
        }
        #pragma unroll
        for (int off = 8; off >= 1; off >>= 1) d += __shfl_xor(d, off);
        #pragma unroll
        for (int g = 0; g < 4; g++) {
            float dg = __shfl(d, g * 16);
            int kg2 = (g == 0) ? k0 : (g == 1) ? k1 : (g == 2) ? k2 : k3;
            if (kg2 >= 0) {
                float e = fmaf(-2.f, dg, cb2q[kg2]);
                if (e < be || (e == be && kg2 < bk)) { be = e; bk = kg2; }
            }
        }
    };

    while (act) {
        int tile = __ffsll(act) - 1; act &= act - 1;
        uint m0 = __shfl((int)mk.x, tile), m1 = __shfl((int)mk.y, tile);
        uint m2 = __shfl((int)mk.z, tile), m3 = __shfl((int)mk.w, tile);
        unsigned long long lo = ((unsigned long long)m1 << 32) | m0;
        unsigned long long hi = ((unsigned long long)m3 << 32) | m2;
        int base = tile * 128;
        while (lo | hi) {
            int c0 = -1, c1 = -1, c2 = -1, c3 = -1;
            #define POP1(dst) \
                if (lo) { int b = __ffsll(lo) - 1; lo &= lo - 1; dst = base + b; } \
                else if (hi) { int b = __ffsll(hi) - 1; hi &= hi - 1; dst = base + 64 + b; }
            POP1(c0) POP1(c1) POP1(c2) POP1(c3)
            #undef POP1
            eval4(c0, c1, c2, c3);
        }
    }
    const int winner = bk;   // identical in all lanes

    if (lane == 0) {
        int b = row >> 11, l = row & (LL - 1);
        idx_out[((size_t)b * QQ + q) * LL + l] = (float)winner;
    }

    const float* cw = cbq + (size_t)winner * DD + lane * 8;
    float4 c0 = *(const float4*)cw;
    float4 c1 = *(const float4*)(cw + 4);
    float4 n0 = make_float4(r0.x - c0.x, r0.y - c0.y, r0.z - c0.z, r0.w - c0.w);
    float4 n1 = make_float4(r1.x - c1.x, r1.y - c1.y, r1.z - c1.z, r1.w - c1.w);

    if (q < QQ - 1) {
        *(float4*)rrow       = n0;
        *(float4*)(rrow + 4) = n1;
        short8 h;
        h[0] = (short)f2bf(n0.x); h[1] = (short)f2bf(n0.y);
        h[2] = (short)f2bf(n0.z); h[3] = (short)f2bf(n0.w);
        h[4] = (short)f2bf(n1.x); h[5] = (short)f2bf(n1.y);
        h[6] = (short)f2bf(n1.z); h[7] = (short)f2bf(n1.w);
        ah[(size_t)row * 64 + lane] = h;   // coalesced 1 KB/row
    } else {
        // final level: quantized = x - resid_final, written directly
        const float* xw = xin + (size_t)row * DD + lane * 8;
        float4 x0 = *(const float4*)xw;
        float4 x1 = *(const float4*)(xw + 4);
        *(float4*)rrow       = make_float4(x0.x - n0.x, x0.y - n0.y, x0.z - n0.z, x0.w - n0.w);
        *(float4*)(rrow + 4) = make_float4(x1.x - n1.x, x1.y - n1.y, x1.z - n1.z, x1.w - n1.w);
    }
}

extern "C" void kernel_launch(void* const* d_in, const int* in_sizes, int n_in,
                              void* d_out, int out_size, void* d_ws, size_t ws_size,
                              hipStream_t stream) {
    (void)in_sizes; (void)n_in; (void)out_size; (void)ws_size;
    const float* x  = (const float*)d_in[0];
    const float* cb = (const float*)d_in[1];
    float* out = (float*)d_out;

    float* idx_out = out;                           // BB*QQ*LL floats
    float* resid   = out + (size_t)BB * QQ * LL;    // doubles as quantized output

    char* w = (char*)d_ws;
    float*  cb2       = (float*)(w);                 // 64 KB
    float*  blockv1   = (float*)(w + 0x10000);       // 1 MB  -> ends 0x110000
    uint4*  blockmask = (uint4*)(w + 0x110000);      // 4 MB  -> ends 0x510000
    short8* ah        = (short8*)(w + 0x510000);     // 16 MB -> ends 0x1510000
    short8* bh2       = (short8*)(w + 0x1510000);    // 2 MB  -> ends 0x1710000 (~24 MB)

    cb2_kernel<<<QQ * KK / 4, 256, 0, stream>>>(cb, cb2);
    aprep0_kernel<<<MM / 4, 256, 0, stream>>>(x, resid, ah);

    for (int q = 0; q < QQ; q++) {
        const float* cbq = cb + (size_t)q * KK * DD;
        const float* c2q = cb2 + (size_t)q * KK;
        const float W = 2.0f + 0.3f * q;   // proven coverage window (R7-R9)

        bprep_kernel<<<KK / 4, 256, 0, stream>>>(cbq, bh2);

        gemm_argmin_kernel<<<512, 512, 0, stream>>>(ah, bh2, c2q,
                                                    blockv1, blockmask, W);

        crru_kernel<<<MM / 4, 256, 0, stream>>>(blockv1, blockmask, cbq, c2q, x,
                                                resid, idx_out, ah, q, W);
    }
}